// Round 1
// baseline (151.019 us; speedup 1.0000x reference)
//
#include <hip/hip_runtime.h>

#define Bn 32
#define Dch 3
#define Tn 16384
#define Ln 16
#define Sn 128
#define Hn 512
#define Cn 10
#define TOUT (Tn - Ln + 1)          // 16369 valid window positions
#define TCHUNK 1024
#define NCHUNK ((TOUT + TCHUNK - 1) / TCHUNK)   // 16
#define TJ 16                        // t-positions per thread

// ---------------------------------------------------------------- init: +inf
__global__ __launch_bounds__(256) void init_inf(unsigned int* out) {
    int i = blockIdx.x * 256 + threadIdx.x;
    if (i < Bn * Sn) out[i] = 0x7F800000u;   // +inf (positive-float int ordering)
}

// ------------------------------------------------------- distance (min-dist)
__global__ __launch_bounds__(256) void dist_kernel(const float* __restrict__ x,
                                                   const float* __restrict__ sh,
                                                   float* __restrict__ dist_out) {
    __shared__ float sh_lds[Sn * 48];                 // 24576 B
    __shared__ float shsq_lds[Sn];                    //   512 B
    __shared__ float x_lds[Dch][TCHUNK + Ln - 1];     // 12468 B

    const int tid   = threadIdx.x;
    const int b     = blockIdx.x / NCHUNK;
    const int chunk = blockIdx.x % NCHUNK;
    const int t0    = chunk * TCHUNK;

    // stage shapelets (flat layout identical to global: s*48 + d*16 + l)
    for (int i = tid; i < Sn * 48; i += 256) sh_lds[i] = sh[i];
    // stage x chunk (guard tail past T)
    {
        const int nx = TCHUNK + Ln - 1; // 1039
        for (int i = tid; i < Dch * nx; i += 256) {
            int d = i / nx, off = i - d * nx;
            int t = t0 + off;
            x_lds[d][off] = (t < Tn) ? x[(b * Dch + d) * Tn + t] : 0.0f;
        }
    }
    __syncthreads();
    if (tid < Sn) {
        float a = 0.f;
        #pragma unroll
        for (int k = 0; k < 48; ++k) { float v = sh_lds[tid * 48 + k]; a = fmaf(v, v, a); }
        shsq_lds[tid] = a;
    }
    __syncthreads();

    // lane = t-group (16 consecutive t); wave-uniform shapelet loop (LDS broadcast)
    const int tgroup = tid & 63;
    const int srole  = tid >> 6;            // 4 roles x 32 shapelets
    const int tloc   = tgroup * TJ;         // [0,1024)
    const int tglob  = t0 + tloc;

    // x window in registers: 3 x 31 floats
    float xr[Dch][TJ + Ln - 1];
    #pragma unroll
    for (int d = 0; d < Dch; ++d)
        #pragma unroll
        for (int i = 0; i < TJ + Ln - 1; ++i)
            xr[d][i] = x_lds[d][tloc + i];

    // window squared-norms (once per thread, amortized over 32 shapelets)
    float winsq[TJ];
    #pragma unroll
    for (int j = 0; j < TJ; ++j) {
        float a = 0.f;
        #pragma unroll
        for (int d = 0; d < Dch; ++d)
            #pragma unroll
            for (int l = 0; l < Ln; ++l)
                a = fmaf(xr[d][j + l], xr[d][j + l], a);
        winsq[j] = a;
    }

    for (int k = 0; k < 32; ++k) {
        const int s = srole * 32 + k;
        float acc[TJ];
        #pragma unroll
        for (int j = 0; j < TJ; ++j) acc[j] = 0.f;
        #pragma unroll
        for (int d = 0; d < Dch; ++d) {
            #pragma unroll
            for (int l = 0; l < Ln; ++l) {
                const float shv = sh_lds[s * 48 + d * 16 + l];   // wave-uniform: broadcast
                #pragma unroll
                for (int j = 0; j < TJ; ++j)
                    acc[j] = fmaf(shv, xr[d][l + j], acc[j]);
            }
        }
        const float ssq = shsq_lds[s];
        float m = __builtin_inff();
        #pragma unroll
        for (int j = 0; j < TJ; ++j) {
            float dist = winsq[j] + ssq - 2.0f * acc[j];
            if (tglob + j < TOUT) m = fminf(m, dist);
        }
        // wave min-reduce (all 64 lanes share s)
        #pragma unroll
        for (int off = 32; off > 0; off >>= 1)
            m = fminf(m, __shfl_xor(m, off, 64));
        if (tgroup == 0)
            atomicMin((int*)&dist_out[b * Sn + s], __float_as_int(fmaxf(m, 0.0f)));
    }
}

// ------------------------------------------------------------- tiny MLP head
__global__ __launch_bounds__(512) void mlp_kernel(const float* __restrict__ dist,
                                                  const float* __restrict__ W1,
                                                  const float* __restrict__ b1,
                                                  const float* __restrict__ W2,
                                                  const float* __restrict__ b2,
                                                  float* __restrict__ cls) {
    __shared__ float db[Sn];
    __shared__ float hb[Hn];
    __shared__ float part[Cn][32];
    const int b = blockIdx.x, tid = threadIdx.x;
    if (tid < Sn) db[tid] = dist[b * Sn + tid];
    __syncthreads();
    float a = b1[tid];
    #pragma unroll 8
    for (int s = 0; s < Sn; ++s) a = fmaf(db[s], W1[tid * Sn + s], a);
    hb[tid] = fmaxf(a, 0.0f);
    __syncthreads();
    if (tid < Cn * 32) {
        const int c = tid >> 5, p = tid & 31;
        float acc = 0.f;
        #pragma unroll
        for (int i = 0; i < Hn / 32; ++i)
            acc = fmaf(hb[p + 32 * i], W2[c * Hn + p + 32 * i], acc);
        part[c][p] = acc;
    }
    __syncthreads();
    if (tid < Cn) {
        float acc = b2[tid];
        for (int p = 0; p < 32; ++p) acc += part[tid][p];
        cls[b * Cn + tid] = acc;
    }
}

// ----------------------------------------------------------------- launcher
extern "C" void kernel_launch(void* const* d_in, const int* in_sizes, int n_in,
                              void* d_out, int out_size, void* d_ws, size_t ws_size,
                              hipStream_t stream) {
    const float* x  = (const float*)d_in[0];
    const float* sh = (const float*)d_in[1];
    const float* W1 = (const float*)d_in[2];
    const float* b1 = (const float*)d_in[3];
    const float* W2 = (const float*)d_in[4];
    const float* b2 = (const float*)d_in[5];
    float* out = (float*)d_out;

    init_inf<<<(Bn * Sn + 255) / 256, 256, 0, stream>>>((unsigned int*)out);
    dist_kernel<<<Bn * NCHUNK, 256, 0, stream>>>(x, sh, out);
    mlp_kernel<<<Bn, 512, 0, stream>>>(out, W1, b1, W2, b2, out + Bn * Sn);
}

// Round 2
// 104.384 us; speedup vs baseline: 1.4468x; 1.4468x over previous
//
#include <hip/hip_runtime.h>
#include <hip/hip_bf16.h>

#define Bn 32
#define Tn 16384
#define Ln 16
#define Sn 128
#define Hn 512
#define Cn 10
#define Kn 48
#define TOUT 16369
#define CH 1024
#define NCH 16
#define XLEN 1048   // CH + 24 slack; per phase/channel array, 16B-aligned pitch (2096 B)

typedef short  s16x8  __attribute__((ext_vector_type(8)));
typedef float  f32x16 __attribute__((ext_vector_type(16)));

__device__ __forceinline__ unsigned short f2bf(float f) {
    union { float f; unsigned int u; } v; v.f = f;
    unsigned int r = v.u + 0x7FFF + ((v.u >> 16) & 1);   // RNE
    return (unsigned short)(r >> 16);
}

// ---------------------------------------------------------------- distance
__global__ __launch_bounds__(256, 2) void dist_kernel(const float* __restrict__ x,
                                                      const float* __restrict__ sh,
                                                      float* __restrict__ partial) {
    __shared__ unsigned short xph[24 * XLEN];   // 50304 B; aliased as fp32 shapelet stage first
    __shared__ float winsq_lds[CH];             // 4096 B
    __shared__ float wavemin[4 * Sn];           // 2048 B

    const int tid   = threadIdx.x;
    const int b     = blockIdx.x >> 4;
    const int chunk = blockIdx.x & 15;
    const int tb    = chunk * CH;
    const int lane  = tid & 63;
    const int w     = tid >> 6;
    const int n     = lane & 31;     // MFMA row (A) / col (B,C)
    const int h     = lane >> 5;     // k-half select

    // ---- 1) stage shapelets fp32 -> LDS (aliased region)
    float* shf = (float*)xph;        // 6144 floats = 24576 B < 50304 B
    {
        const float4* s4 = (const float4*)sh;
        for (int i = tid; i < Sn * Kn / 4; i += 256) ((float4*)shf)[i] = s4[i];
    }
    __syncthreads();

    // ---- 2) build B-fragments (shapelets * -2, bf16) + shsq (fp32 exact)
    s16x8 bfr[3][4];
    float shsqv[4];
    #pragma unroll
    for (int st = 0; st < 4; ++st) {
        const int s = st * 32 + n;
        const float* row = shf + s * Kn;
        float q = 0.f;
        #pragma unroll
        for (int k = 0; k < Kn; ++k) q = fmaf(row[k], row[k], q);
        shsqv[st] = q;
        #pragma unroll
        for (int kk = 0; kk < 3; ++kk)
            #pragma unroll
            for (int j = 0; j < 8; ++j)
                bfr[kk][st][j] = (short)f2bf(-2.0f * row[kk * 16 + 8 * h + j]);
    }
    __syncthreads();   // done reading shf; xph region free

    // ---- 3) stage x chunk as 8 phase-shifted bf16 copies
    // xph[p][d][u] = bf16(x[b][d][tb + u + p])
    const float* xb = x + b * 3 * Tn;
    for (int p = 0; p < 8; ++p) {
        for (int idx = tid; idx < 3 * (XLEN / 2); idx += 256) {
            const int d = idx / (XLEN / 2);
            const int e = idx - d * (XLEN / 2);
            const int u = 2 * e;
            const int t0 = tb + u + p;
            const float f0 = (t0     < Tn) ? xb[d * Tn + t0]     : 0.f;
            const float f1 = (t0 + 1 < Tn) ? xb[d * Tn + t0 + 1] : 0.f;
            const unsigned int packed = (unsigned int)f2bf(f0) | ((unsigned int)f2bf(f1) << 16);
            *(unsigned int*)(void*)&xph[(p * 3 + d) * XLEN + u] = packed;
        }
    }

    // ---- 4) winsq fp32 (exact, sliding window from global; L1-warm)
    {
        const int i0 = tid * 4;
        const int t0 = tb + i0;
        float q0 = 0.f, q1 = 0.f, q2 = 0.f, q3 = 0.f;
        #pragma unroll
        for (int d = 0; d < 3; ++d) {
            const float* xd = xb + d * Tn + t0;
            float wv[19];
            #pragma unroll
            for (int l = 0; l < 19; ++l) wv[l] = (t0 + l < Tn) ? xd[l] : 0.f;
            float s = 0.f;
            #pragma unroll
            for (int l = 0; l < 16; ++l) s = fmaf(wv[l], wv[l], s);
            q0 += s;
            s = s - wv[0] * wv[0] + wv[16] * wv[16]; q1 += s;
            s = s - wv[1] * wv[1] + wv[17] * wv[17]; q2 += s;
            s = s - wv[2] * wv[2] + wv[18] * wv[18]; q3 += s;
        }
        winsq_lds[i0    ] = (tb + i0     >= TOUT) ? 1e30f : q0;
        winsq_lds[i0 + 1] = (tb + i0 + 1 >= TOUT) ? 1e30f : q1;
        winsq_lds[i0 + 2] = (tb + i0 + 2 >= TOUT) ? 1e30f : q2;
        winsq_lds[i0 + 3] = (tb + i0 + 3 >= TOUT) ? 1e30f : q3;
    }
    __syncthreads();

    // ---- 5) main MFMA loop: 8 tiles per wave; tile rows t = tb + i + 16*m
    f32x16 zero16 = {0.f, 0.f, 0.f, 0.f, 0.f, 0.f, 0.f, 0.f,
                     0.f, 0.f, 0.f, 0.f, 0.f, 0.f, 0.f, 0.f};
    float mcol[4] = {1e30f, 1e30f, 1e30f, 1e30f};
    const int g = w >> 1;
    const int rbase = 8 * (w & 1);

    for (int rr = 0; rr < 8; ++rr) {
        const int i  = (g << 9) + rbase + rr;   // tile base offset in chunk
        const int p  = i & 7;                   // phase copy (tb % 8 == 0)
        const int ib = i - p;                   // 8-aligned
        const int u0 = ib + 16 * n + 8 * h;     // 16B-aligned element offset
        const unsigned short* xp = &xph[p * 3 * XLEN + u0];
        const s16x8 a0 = *(const s16x8*)(const void*)(xp);
        const s16x8 a1 = *(const s16x8*)(const void*)(xp + XLEN);
        const s16x8 a2 = *(const s16x8*)(const void*)(xp + 2 * XLEN);

        f32x16 acc[4];
        #pragma unroll
        for (int st = 0; st < 4; ++st) {
            acc[st] = __builtin_amdgcn_mfma_f32_32x32x16_bf16(a0, bfr[0][st], zero16, 0, 0, 0);
            acc[st] = __builtin_amdgcn_mfma_f32_32x32x16_bf16(a1, bfr[1][st], acc[st], 0, 0, 0);
            acc[st] = __builtin_amdgcn_mfma_f32_32x32x16_bf16(a2, bfr[2][st], acc[st], 0, 0, 0);
        }

        float wq[16];
        #pragma unroll
        for (int reg = 0; reg < 16; ++reg) {
            const int row = (reg & 3) + 8 * (reg >> 2) + 4 * h;
            wq[reg] = winsq_lds[i + 16 * row];
        }
        #pragma unroll
        for (int st = 0; st < 4; ++st)
            #pragma unroll
            for (int reg = 0; reg < 16; ++reg) {
                const float v = acc[st][reg] + wq[reg] + shsqv[st];
                mcol[st] = fminf(mcol[st], v);
            }
    }

    // ---- 6) reduce: lane n & n+32 share column s = st*32+n
    #pragma unroll
    for (int st = 0; st < 4; ++st) {
        float mm = mcol[st];
        mm = fminf(mm, __shfl_xor(mm, 32, 64));
        if (h == 0) wavemin[w * Sn + st * 32 + n] = mm;
    }
    __syncthreads();
    if (tid < Sn) {
        const float mm = fminf(fminf(wavemin[tid], wavemin[Sn + tid]),
                               fminf(wavemin[2 * Sn + tid], wavemin[3 * Sn + tid]));
        partial[(b * NCH + chunk) * Sn + tid] = mm;
    }
}

// ------------------------------------------- final min over chunks + MLP head
__global__ __launch_bounds__(512) void mlp_kernel(const float* __restrict__ partial,
                                                  const float* __restrict__ W1,
                                                  const float* __restrict__ b1,
                                                  const float* __restrict__ W2,
                                                  const float* __restrict__ b2,
                                                  float* __restrict__ out) {
    __shared__ float db[Sn];
    __shared__ float hb[Hn];
    __shared__ float part[Cn][32];
    const int b = blockIdx.x, tid = threadIdx.x;

    if (tid < Sn) {
        float mm = 1e30f;
        #pragma unroll
        for (int ch = 0; ch < NCH; ++ch)
            mm = fminf(mm, partial[(b * NCH + ch) * Sn + tid]);
        db[tid] = mm;
        out[b * Sn + tid] = mm;            // distance output
    }
    __syncthreads();

    float a = b1[tid];
    const float4* w1r = (const float4*)(W1 + tid * Sn);
    const float4* dbv = (const float4*)db;
    #pragma unroll 8
    for (int i = 0; i < Sn / 4; ++i) {
        const float4 wv = w1r[i];
        const float4 dv = dbv[i];
        a = fmaf(dv.x, wv.x, a); a = fmaf(dv.y, wv.y, a);
        a = fmaf(dv.z, wv.z, a); a = fmaf(dv.w, wv.w, a);
    }
    hb[tid] = fmaxf(a, 0.0f);
    __syncthreads();

    if (tid < Cn * 32) {
        const int c = tid >> 5, p = tid & 31;
        float acc = 0.f;
        #pragma unroll
        for (int i = 0; i < Hn / 32; ++i)
            acc = fmaf(hb[p + 32 * i], W2[c * Hn + p + 32 * i], acc);
        part[c][p] = acc;
    }
    __syncthreads();
    if (tid < Cn) {
        float acc = b2[tid];
        for (int p = 0; p < 32; ++p) acc += part[tid][p];
        out[Bn * Sn + b * Cn + tid] = acc;  // classification output
    }
}

// ----------------------------------------------------------------- launcher
extern "C" void kernel_launch(void* const* d_in, const int* in_sizes, int n_in,
                              void* d_out, int out_size, void* d_ws, size_t ws_size,
                              hipStream_t stream) {
    const float* x  = (const float*)d_in[0];
    const float* sh = (const float*)d_in[1];
    const float* W1 = (const float*)d_in[2];
    const float* b1 = (const float*)d_in[3];
    const float* W2 = (const float*)d_in[4];
    const float* b2 = (const float*)d_in[5];
    float* out = (float*)d_out;
    float* partial = (float*)d_ws;   // 32*16*128 floats = 256 KB

    dist_kernel<<<Bn * NCH, 256, 0, stream>>>(x, sh, partial);
    mlp_kernel<<<Bn, 512, 0, stream>>>(partial, W1, b1, W2, b2, out);
}